// Round 22
// baseline (224.853 us; speedup 1.0000x reference)
//
#include <hip/hip_runtime.h>

#define N_NODES 100000
#define F_IN 512
#define HID 16
#define F_OUT 40

#define NB 784        // buckets = row >> 7
#define BSHIFT 7
#define ROWS_PB 128
#define BCAP 4608     // mean 4082 + 8 sigma
#define CUR_PAD 16    // gcursor stride in ints (64B line per counter)
#define APAD 17
#define PARTB 512     // part1 blocks in kernel 1
#define G1 777        // gemm blocks in kernel 1
#define NBG 1563      // total gemm blocks (100000/64)
#define SROW 129      // stage buffer row stride (b32 conflict-free)

// ---- bf16 helpers (RNE pack, shift-unpack) ----
__device__ __forceinline__ unsigned int f2bf(float f) {
    unsigned int u = __float_as_uint(f);
    u += 0x7FFFu + ((u >> 16) & 1u);
    return u >> 16;
}
__device__ __forceinline__ float bflo(unsigned int v) { return __uint_as_float(v << 16); }
__device__ __forceinline__ float bfhi(unsigned int v) { return __uint_as_float(v & 0xFFFF0000u); }

// ---- pack W1 [512][16] f32 -> bf16x2 [512][8] (16KB: fits scalar cache) ----
__global__ void k_wpack(const float* __restrict__ W1, unsigned int* __restrict__ Wp) {
    int i = blockIdx.x * 512 + threadIdx.x;
    if (i < F_IN * HID / 2)
        Wp[i] = f2bf(W1[2 * i]) | (f2bf(W1[2 * i + 1]) << 16);
}

// ---- staged GEMM1 body: 64 rows/block, 4 stages x 128k, bf16 W + bf16 Hs ---
__device__ __forceinline__ void gemm_body(const float* __restrict__ x,
                                          const unsigned int* __restrict__ Wp,
                                          unsigned int* __restrict__ Hs16,
                                          int bid, int t, float* smem) {
    int tilebase = bid * 64;
    int srow = t >> 5;            // staging: 16 rows per round, 2 rows/wave
    int sseg = t & 31;            // 32 x float4 per row
    int crow = t & 63;            // compute row
    int ksub = __builtin_amdgcn_readfirstlane(t >> 6);   // 0..7 wave id

    float acc[HID];
#pragma unroll
    for (int f = 0; f < HID; ++f) acc[f] = 0.0f;

    float4 rg[4];
#pragma unroll
    for (int q = 0; q < 4; ++q) {
        int r = tilebase + q * 16 + srow;
        r = min(r, N_NODES - 1);
        rg[q] = *reinterpret_cast<const float4*>(x + (size_t)r * F_IN + sseg * 4);
    }
    for (int s = 0; s < 4; ++s) {
        __syncthreads();    // stage buffer free
#pragma unroll
        for (int q = 0; q < 4; ++q) {
            int base = (q * 16 + srow) * SROW + sseg * 4;
            smem[base + 0] = rg[q].x;
            smem[base + 1] = rg[q].y;
            smem[base + 2] = rg[q].z;
            smem[base + 3] = rg[q].w;
        }
        __syncthreads();    // stage ready
        if (s < 3) {        // prefetch next stage during compute (T14 order)
#pragma unroll
            for (int q = 0; q < 4; ++q) {
                int r = tilebase + q * 16 + srow;
                r = min(r, N_NODES - 1);
                rg[q] = *reinterpret_cast<const float4*>(
                    x + (size_t)r * F_IN + (s + 1) * 128 + sseg * 4);
            }
        }
        const unsigned int* wp = Wp + (s * 128 + ksub * 16) * 8;
        int lbase = crow * SROW + ksub * 16;
#pragma unroll
        for (int kk = 0; kk < 16; ++kk) {
            float xv = smem[lbase + kk];
#pragma unroll
            for (int fp = 0; fp < 8; ++fp) {
                unsigned int wv = wp[kk * 8 + fp];   // s_load (wave-uniform)
                acc[2 * fp]     = fmaf(xv, bflo(wv), acc[2 * fp]);
                acc[2 * fp + 1] = fmaf(xv, bfhi(wv), acc[2 * fp + 1]);
            }
        }
    }
    __syncthreads();
    int rbase = (ksub * 64 + crow) * APAD;
#pragma unroll
    for (int f = 0; f < HID; ++f) smem[rbase + f] = acc[f];
    __syncthreads();
    // epilogue: thread = (row, feature-pair); one dword bf16x2 store
    {
        int r = t >> 3, fp = (t & 7) * 2;
        int rgl = tilebase + r;
        if (rgl < N_NODES) {
            float s0 = 0.0f, s1 = 0.0f;
#pragma unroll
            for (int c = 0; c < 8; ++c) {
                s0 += smem[(c * 64 + r) * APAD + fp];
                s1 += smem[(c * 64 + r) * APAD + fp + 1];
            }
            Hs16[(size_t)rgl * 8 + (fp >> 1)] = f2bf(s0) | (f2bf(s1) << 16);
        }
    }
}

// ---- kernel 1: blocks [0,PARTB) = part1 scatter; rest = gemm [0,G1) --------
__global__ __launch_bounds__(512) void k_p1g(const float* __restrict__ x,
                                             const unsigned int* __restrict__ Wp,
                                             const int* __restrict__ ei, int E,
                                             int* __restrict__ gcursor,
                                             unsigned int* __restrict__ sortbuf,
                                             unsigned int* __restrict__ Hs16) {
    __shared__ float smem[8704];   // 34816 B union
    int t = threadIdx.x;
    if (blockIdx.x < PARTB) {
        int* lcnt0 = (int*)smem;        // NB
        int* lcnt1 = lcnt0 + NB;        // NB
        int* gb    = lcnt1 + NB;        // NB
        int half = (t >> 6) & 1;
        int* myl = half ? lcnt1 : lcnt0;
        int epb = (E + PARTB - 1) / PARTB;        // 6250
        int base = blockIdx.x * epb;
        int lim = min(base + epb, E);
        for (int i = t; i < NB; i += 512) { lcnt0[i] = 0; lcnt1[i] = 0; }
        __syncthreads();
        unsigned int v[13]; int bkt[13], mi[13];
#pragma unroll
        for (int i = 0; i < 13; ++i) {
            int e = base + i * 512 + t;
            bkt[i] = -1;
            if (e < lim) {
                int r = ei[e], c = ei[E + e];
                bkt[i] = r >> BSHIFT;
                v[i] = ((unsigned)(r & (ROWS_PB - 1)) << 17) | (unsigned)c;
                mi[i] = atomicAdd(&myl[bkt[i]], 1);
            }
        }
        __syncthreads();
        for (int i = t; i < NB; i += 512)
            gb[i] = atomicAdd(&gcursor[i * CUR_PAD], lcnt0[i] + lcnt1[i]);
        __syncthreads();
#pragma unroll
        for (int i = 0; i < 13; ++i)
            if (bkt[i] >= 0) {
                int slot = gb[bkt[i]] + (half ? lcnt0[bkt[i]] : 0) + mi[i];
                if (slot < BCAP) sortbuf[(size_t)bkt[i] * BCAP + slot] = v[i];
            }
    } else {
        gemm_body(x, Wp, Hs16, blockIdx.x - PARTB, t, smem);
    }
}

// ---- kernel 2: blocks [0,NB) = CSR build (512t); rest = gemm [G1,NBG) ------
__global__ __launch_bounds__(512) void k_bg(const float* __restrict__ x,
                                            const unsigned int* __restrict__ Wp,
                                            const unsigned int* __restrict__ sortbuf,
                                            const int* __restrict__ gcursor,
                                            int* __restrict__ rowptr,
                                            float* __restrict__ dinv,
                                            int* __restrict__ colv,
                                            unsigned int* __restrict__ Hs16) {
    __shared__ float smem[8704];   // 34816 B union
    int t = threadIdx.x;
    if (blockIdx.x < NB) {
        int* ib     = (int*)smem;
        int* bb     = ib;               // 784
        int* s      = ib + 784;         // 256
        int* hist   = ib + 1040;        // 128
        int* rstart = ib + 1168;        // 128
        int* cur    = ib + 1296;        // 128
        int b = blockIdx.x;

        int l0 = 0, l1 = 0, l2 = 0, l3 = 0;
        if (t < 196) {
            l0 = min(gcursor[(t * 4 + 0) * CUR_PAD], BCAP);
            l1 = min(gcursor[(t * 4 + 1) * CUR_PAD], BCAP);
            l2 = min(gcursor[(t * 4 + 2) * CUR_PAD], BCAP);
            l3 = min(gcursor[(t * 4 + 3) * CUR_PAD], BCAP);
        }
        int part = l0 + l1 + l2 + l3;
        if (t < 256) s[t] = (t < 196) ? part : 0;
        __syncthreads();
        for (int off = 1; off < 256; off <<= 1) {
            int a = 0;
            if (t < 256 && t >= off) a = s[t - off];
            __syncthreads();
            if (t < 256) s[t] += a;
            __syncthreads();
        }
        if (t < 196) {
            int ex = s[t] - part;
            bb[t * 4 + 0] = ex;
            bb[t * 4 + 1] = ex + l0;
            bb[t * 4 + 2] = ex + l0 + l1;
            bb[t * 4 + 3] = ex + l0 + l1 + l2;
        }
        if (t < ROWS_PB) hist[t] = 0;
        if (b == 0 && t == 255) rowptr[N_NODES] = s[255];
        __syncthreads();
        int gbase = bb[b];
        int n = min(gcursor[b * CUR_PAD], BCAP);

        const unsigned int* sb = sortbuf + (size_t)b * BCAP;
        for (int i = t; i < n; i += 512) atomicAdd(&hist[sb[i] >> 17], 1);
        __syncthreads();
        int c0 = (t < ROWS_PB) ? hist[t] : 0;
        if (t < 256) s[t] = (t < ROWS_PB) ? c0 : 0;
        __syncthreads();
        for (int off = 1; off < ROWS_PB; off <<= 1) {
            int a = 0;
            if (t < ROWS_PB && t >= off) a = s[t - off];
            __syncthreads();
            if (t < ROWS_PB) s[t] += a;
            __syncthreads();
        }
        if (t < ROWS_PB) {
            int ex = s[t] - c0;
            rstart[t] = ex;
            cur[t] = 0;
            int g = b * ROWS_PB + t;
            if (g < N_NODES) {
                rowptr[g] = gbase + ex;
                dinv[g] = rsqrtf((float)(c0 + 1));   // +1 self-loop
            }
        }
        __syncthreads();
        for (int i = t; i < n; i += 512) {
            unsigned int v = sb[i];
            int lr = v >> 17;
            int pos = atomicAdd(&cur[lr], 1);
            colv[gbase + rstart[lr] + pos] = (int)(v & 0x1FFFFu);
        }
    } else {
        gemm_body(x, Wp, Hs16, G1 + (blockIdx.x - NB), t, smem);
    }
}

// -- agg1: wave/node pull of bf16 Hs, dinv[c] per edge, bias+relu, bf16 out --
__global__ __launch_bounds__(256) void k_agg1(const int* __restrict__ rowptr,
                                              const int* __restrict__ colv,
                                              const float* __restrict__ dinv,
                                              const unsigned int* __restrict__ Hs16,
                                              const float* __restrict__ b1,
                                              unsigned int* __restrict__ h1s16) {
    int wid = __builtin_amdgcn_readfirstlane((blockIdx.x * 256 + threadIdx.x) >> 6);
    if (wid >= N_NODES) return;
    int lane = threadIdx.x & 63;
    int f4 = lane & 3, sub = lane >> 2;
    int beg = rowptr[wid], end = rowptr[wid + 1];   // s_load (wid scalar)
    float dr = dinv[wid];                            // s_load
    float4 acc = make_float4(0.f, 0.f, 0.f, 0.f);
    for (int j = beg + sub; j < end; j += 16) {
        int c = colv[j];
        float dc = dinv[c];                          // 4 lanes share c
        uint2 hv = *reinterpret_cast<const uint2*>(Hs16 + (size_t)c * 8 + f4 * 2);
        acc.x = fmaf(bflo(hv.x), dc, acc.x);
        acc.y = fmaf(bfhi(hv.x), dc, acc.y);
        acc.z = fmaf(bflo(hv.y), dc, acc.z);
        acc.w = fmaf(bfhi(hv.y), dc, acc.w);
    }
#pragma unroll
    for (int d = 4; d < 64; d <<= 1) {
        acc.x += __shfl_xor(acc.x, d);
        acc.y += __shfl_xor(acc.y, d);
        acc.z += __shfl_xor(acc.z, d);
        acc.w += __shfl_xor(acc.w, d);
    }
    if (sub == 0) {
        uint2 sv = *reinterpret_cast<const uint2*>(Hs16 + (size_t)wid * 8 + f4 * 2);
        float4 bb = *reinterpret_cast<const float4*>(b1 + f4 * 4);
        float o0 = fmaxf((acc.x + bflo(sv.x) * dr) * dr + bb.x, 0.f) * dr;
        float o1 = fmaxf((acc.y + bfhi(sv.x) * dr) * dr + bb.y, 0.f) * dr;
        float o2 = fmaxf((acc.z + bflo(sv.y) * dr) * dr + bb.z, 0.f) * dr;
        float o3 = fmaxf((acc.w + bfhi(sv.y) * dr) * dr + bb.w, 0.f) * dr;
        uint2 pk;
        pk.x = f2bf(o0) | (f2bf(o1) << 16);
        pk.y = f2bf(o2) | (f2bf(o3) << 16);
        *reinterpret_cast<uint2*>(h1s16 + (size_t)wid * 8 + f4 * 2) = pk;
    }
}

// -- agg2: wave/node pull of bf16 h1s, fused 16x40 GEMM + bias -> out (f32) --
__global__ __launch_bounds__(256) void k_agg2(const int* __restrict__ rowptr,
                                              const int* __restrict__ colv,
                                              const float* __restrict__ dinv,
                                              const unsigned int* __restrict__ h1s16,
                                              const float* __restrict__ W2,
                                              const float* __restrict__ b2,
                                              float* __restrict__ out) {
    int wid = __builtin_amdgcn_readfirstlane((blockIdx.x * 256 + threadIdx.x) >> 6);
    if (wid >= N_NODES) return;
    int lane = threadIdx.x & 63;
    int f4 = lane & 3, sub = lane >> 2;
    int beg = rowptr[wid], end = rowptr[wid + 1];   // s_load
    float dr = dinv[wid];                            // s_load
    float4 acc = make_float4(0.f, 0.f, 0.f, 0.f);
    for (int j = beg + sub; j < end; j += 16) {
        int c = colv[j];
        uint2 hv = *reinterpret_cast<const uint2*>(h1s16 + (size_t)c * 8 + f4 * 2);
        acc.x += bflo(hv.x);
        acc.y += bfhi(hv.x);
        acc.z += bflo(hv.y);
        acc.w += bfhi(hv.y);
    }
#pragma unroll
    for (int d = 4; d < 64; d <<= 1) {
        acc.x += __shfl_xor(acc.x, d);
        acc.y += __shfl_xor(acc.y, d);
        acc.z += __shfl_xor(acc.z, d);
        acc.w += __shfl_xor(acc.w, d);
    }
    uint2 sv = *reinterpret_cast<const uint2*>(h1s16 + (size_t)wid * 8 + f4 * 2);
    float4 w4;
    w4.x = (acc.x + bflo(sv.x)) * dr;
    w4.y = (acc.y + bfhi(sv.x)) * dr;
    w4.z = (acc.z + bflo(sv.y)) * dr;
    w4.w = (acc.w + bfhi(sv.y)) * dr;
    if (lane < F_OUT) {
        float o = b2[lane];
#pragma unroll
        for (int k = 0; k < HID; ++k) {
            float comp = (k & 3) == 0 ? w4.x : (k & 3) == 1 ? w4.y
                        : (k & 3) == 2 ? w4.z : w4.w;
            float wk = __shfl(comp, k >> 2);   // lane k>>2 holds f4 == k>>2
            o = fmaf(wk, W2[k * F_OUT + lane], o);
        }
        out[(size_t)wid * F_OUT + lane] = o;
    }
}

// ---------------- launch ----------------
extern "C" void kernel_launch(void* const* d_in, const int* in_sizes, int n_in,
                              void* d_out, int out_size, void* d_ws, size_t ws_size,
                              hipStream_t stream) {
    const float* x  = (const float*)d_in[0];
    const int* ei   = (const int*)d_in[1];      // int32 [2][E]
    const float* W1 = (const float*)d_in[2];
    const float* b1 = (const float*)d_in[3];
    const float* W2 = (const float*)d_in[4];
    const float* b2 = (const float*)d_in[5];
    float* out = (float*)d_out;
    const int E = in_sizes[1] / 2;

    // ws layout (4B units)
    int* gcursor          = (int*)d_ws;                      // 12544
    unsigned int* Wp      = (unsigned int*)(gcursor + 12544);// 4096 (bf16 W1)
    int* rowptr           = (int*)(Wp + 4096);               // 100016
    float* dinv           = (float*)(rowptr + 100016);       // 100032
    int* colv             = (int*)(dinv + 100032);           // 3,200,000
    unsigned int* sortbuf = (unsigned int*)(colv + 3200000); // 3,612,672
    unsigned int* h1s16   = sortbuf;                         // alias: dead after k_bg
    unsigned int* Hs16    = sortbuf + 3612672;               // 800,032 (bf16 x2)
    // total ~29 MB

    const int nbW = (N_NODES * 64 + 255) / 256;    // 25000 (wave per node)

    hipMemsetAsync(gcursor, 0, (size_t)NB * CUR_PAD * sizeof(int), stream);
    k_wpack<<<8, 512, 0, stream>>>(W1, Wp);
    k_p1g<<<PARTB + G1, 512, 0, stream>>>(x, Wp, ei, E, gcursor, sortbuf, Hs16);
    k_bg<<<NB + (NBG - G1), 512, 0, stream>>>(x, Wp, sortbuf, gcursor,
                                              rowptr, dinv, colv, Hs16);
    k_agg1<<<nbW, 256, 0, stream>>>(rowptr, colv, dinv, Hs16, b1, h1s16);
    k_agg2<<<nbW, 256, 0, stream>>>(rowptr, colv, dinv, h1s16, W2, b2, out);
}

// Round 23
// 195.498 us; speedup vs baseline: 1.1502x; 1.1502x over previous
//
#include <hip/hip_runtime.h>

#define N_NODES 100000
#define F_IN 512
#define HID 16
#define F_OUT 40

#define NB 784        // buckets = row >> 7
#define BSHIFT 7
#define ROWS_PB 128
#define BCAP 4608     // mean 4082 + 8 sigma
#define CUR_PAD 16    // gcursor stride in ints (64B line per counter)
#define APAD 17
#define PARTB 512     // part1 blocks in kernel 1
#define G1 777        // gemm blocks in kernel 1
#define NBG 1563      // total gemm blocks (100000/64)
#define SROW 129      // stage buffer row stride (b32 conflict-free)

// ---- bf16 helpers (RNE pack, shift-unpack) ----
__device__ __forceinline__ unsigned int f2bf(float f) {
    unsigned int u = __float_as_uint(f);
    u += 0x7FFFu + ((u >> 16) & 1u);
    return u >> 16;
}
__device__ __forceinline__ float bflo(unsigned int v) { return __uint_as_float(v << 16); }
__device__ __forceinline__ float bfhi(unsigned int v) { return __uint_as_float(v & 0xFFFF0000u); }

// ---- staged GEMM1 body: 64 rows/block, 4 stages x 128k, f32 W, bf16 Hs ----
__device__ __forceinline__ void gemm_body(const float* __restrict__ x,
                                          const float* __restrict__ W1,
                                          unsigned int* __restrict__ Hs16,
                                          int bid, int t, float* smem) {
    int tilebase = bid * 64;
    int srow = t >> 5;            // staging: 16 rows per round, 2 rows/wave
    int sseg = t & 31;            // 32 x float4 per row
    int crow = t & 63;            // compute row
    int ksub = __builtin_amdgcn_readfirstlane(t >> 6);   // 0..7 wave id

    float acc[HID];
#pragma unroll
    for (int f = 0; f < HID; ++f) acc[f] = 0.0f;

    float4 rg[4];
#pragma unroll
    for (int q = 0; q < 4; ++q) {
        int r = tilebase + q * 16 + srow;
        r = min(r, N_NODES - 1);
        rg[q] = *reinterpret_cast<const float4*>(x + (size_t)r * F_IN + sseg * 4);
    }
    for (int s = 0; s < 4; ++s) {
        __syncthreads();    // stage buffer free
#pragma unroll
        for (int q = 0; q < 4; ++q) {
            int base = (q * 16 + srow) * SROW + sseg * 4;
            smem[base + 0] = rg[q].x;
            smem[base + 1] = rg[q].y;
            smem[base + 2] = rg[q].z;
            smem[base + 3] = rg[q].w;
        }
        __syncthreads();    // stage ready
        if (s < 3) {        // prefetch next stage during compute (T14 order)
#pragma unroll
            for (int q = 0; q < 4; ++q) {
                int r = tilebase + q * 16 + srow;
                r = min(r, N_NODES - 1);
                rg[q] = *reinterpret_cast<const float4*>(
                    x + (size_t)r * F_IN + (s + 1) * 128 + sseg * 4);
            }
        }
        const float* wp = W1 + (s * 128 + ksub * 16) * HID;
        int lbase = crow * SROW + ksub * 16;
#pragma unroll
        for (int kk = 0; kk < 16; ++kk) {
            float xv = smem[lbase + kk];
#pragma unroll
            for (int f = 0; f < HID; ++f)
                acc[f] = fmaf(xv, wp[kk * HID + f], acc[f]);  // s_load
        }
    }
    __syncthreads();
    int rbase = (ksub * 64 + crow) * APAD;
#pragma unroll
    for (int f = 0; f < HID; ++f) smem[rbase + f] = acc[f];
    __syncthreads();
    // epilogue: thread = (row, feature-pair); one dword bf16x2 store
    {
        int r = t >> 3, fp = (t & 7) * 2;
        int rgl = tilebase + r;
        if (rgl < N_NODES) {
            float s0 = 0.0f, s1 = 0.0f;
#pragma unroll
            for (int c = 0; c < 8; ++c) {
                s0 += smem[(c * 64 + r) * APAD + fp];
                s1 += smem[(c * 64 + r) * APAD + fp + 1];
            }
            Hs16[(size_t)rgl * 8 + (fp >> 1)] = f2bf(s0) | (f2bf(s1) << 16);
        }
    }
}

// ---- kernel 1: blocks [0,PARTB) = part1 scatter; rest = gemm [0,G1) --------
__global__ __launch_bounds__(512) void k_p1g(const float* __restrict__ x,
                                             const float* __restrict__ W1,
                                             const int* __restrict__ ei, int E,
                                             int* __restrict__ gcursor,
                                             unsigned int* __restrict__ sortbuf,
                                             unsigned int* __restrict__ Hs16) {
    __shared__ float smem[8704];   // 34816 B union
    int t = threadIdx.x;
    if (blockIdx.x < PARTB) {
        int* lcnt0 = (int*)smem;        // NB
        int* lcnt1 = lcnt0 + NB;        // NB
        int* gb    = lcnt1 + NB;        // NB
        int half = (t >> 6) & 1;
        int* myl = half ? lcnt1 : lcnt0;
        int epb = (E + PARTB - 1) / PARTB;        // 6250
        int base = blockIdx.x * epb;
        int lim = min(base + epb, E);
        for (int i = t; i < NB; i += 512) { lcnt0[i] = 0; lcnt1[i] = 0; }
        __syncthreads();
        unsigned int v[13]; int bkt[13], mi[13];
#pragma unroll
        for (int i = 0; i < 13; ++i) {
            int e = base + i * 512 + t;
            bkt[i] = -1;
            if (e < lim) {
                int r = ei[e], c = ei[E + e];
                bkt[i] = r >> BSHIFT;
                v[i] = ((unsigned)(r & (ROWS_PB - 1)) << 17) | (unsigned)c;
                mi[i] = atomicAdd(&myl[bkt[i]], 1);
            }
        }
        __syncthreads();
        for (int i = t; i < NB; i += 512)
            gb[i] = atomicAdd(&gcursor[i * CUR_PAD], lcnt0[i] + lcnt1[i]);
        __syncthreads();
#pragma unroll
        for (int i = 0; i < 13; ++i)
            if (bkt[i] >= 0) {
                int slot = gb[bkt[i]] + (half ? lcnt0[bkt[i]] : 0) + mi[i];
                if (slot < BCAP) sortbuf[(size_t)bkt[i] * BCAP + slot] = v[i];
            }
    } else {
        gemm_body(x, W1, Hs16, blockIdx.x - PARTB, t, smem);
    }
}

// ---- kernel 2: blocks [0,NB) = CSR build (512t); rest = gemm [G1,NBG) ------
__global__ __launch_bounds__(512) void k_bg(const float* __restrict__ x,
                                            const float* __restrict__ W1,
                                            const unsigned int* __restrict__ sortbuf,
                                            const int* __restrict__ gcursor,
                                            int* __restrict__ rowptr,
                                            float* __restrict__ dinv,
                                            int* __restrict__ colv,
                                            unsigned int* __restrict__ Hs16) {
    __shared__ float smem[8704];   // 34816 B union
    int t = threadIdx.x;
    if (blockIdx.x < NB) {
        int* ib     = (int*)smem;
        int* bb     = ib;               // 784
        int* s      = ib + 784;         // 256
        int* hist   = ib + 1040;        // 128
        int* rstart = ib + 1168;        // 128
        int* cur    = ib + 1296;        // 128
        int b = blockIdx.x;

        int l0 = 0, l1 = 0, l2 = 0, l3 = 0;
        if (t < 196) {
            l0 = min(gcursor[(t * 4 + 0) * CUR_PAD], BCAP);
            l1 = min(gcursor[(t * 4 + 1) * CUR_PAD], BCAP);
            l2 = min(gcursor[(t * 4 + 2) * CUR_PAD], BCAP);
            l3 = min(gcursor[(t * 4 + 3) * CUR_PAD], BCAP);
        }
        int part = l0 + l1 + l2 + l3;
        if (t < 256) s[t] = (t < 196) ? part : 0;
        __syncthreads();
        for (int off = 1; off < 256; off <<= 1) {
            int a = 0;
            if (t < 256 && t >= off) a = s[t - off];
            __syncthreads();
            if (t < 256) s[t] += a;
            __syncthreads();
        }
        if (t < 196) {
            int ex = s[t] - part;
            bb[t * 4 + 0] = ex;
            bb[t * 4 + 1] = ex + l0;
            bb[t * 4 + 2] = ex + l0 + l1;
            bb[t * 4 + 3] = ex + l0 + l1 + l2;
        }
        if (t < ROWS_PB) hist[t] = 0;
        if (b == 0 && t == 255) rowptr[N_NODES] = s[255];
        __syncthreads();
        int gbase = bb[b];
        int n = min(gcursor[b * CUR_PAD], BCAP);

        const unsigned int* sb = sortbuf + (size_t)b * BCAP;
        for (int i = t; i < n; i += 512) atomicAdd(&hist[sb[i] >> 17], 1);
        __syncthreads();
        int c0 = (t < ROWS_PB) ? hist[t] : 0;
        if (t < 256) s[t] = (t < ROWS_PB) ? c0 : 0;
        __syncthreads();
        for (int off = 1; off < ROWS_PB; off <<= 1) {
            int a = 0;
            if (t < ROWS_PB && t >= off) a = s[t - off];
            __syncthreads();
            if (t < ROWS_PB) s[t] += a;
            __syncthreads();
        }
        if (t < ROWS_PB) {
            int ex = s[t] - c0;
            rstart[t] = ex;
            cur[t] = 0;
            int g = b * ROWS_PB + t;
            if (g < N_NODES) {
                rowptr[g] = gbase + ex;
                dinv[g] = rsqrtf((float)(c0 + 1));   // +1 self-loop
            }
        }
        __syncthreads();
        for (int i = t; i < n; i += 512) {
            unsigned int v = sb[i];
            int lr = v >> 17;
            int pos = atomicAdd(&cur[lr], 1);
            colv[gbase + rstart[lr] + pos] = (int)(v & 0x1FFFFu);
        }
    } else {
        gemm_body(x, W1, Hs16, G1 + (blockIdx.x - NB), t, smem);
    }
}

// -- agg1: wave/node pull of bf16 Hs, dinv[c] per edge, bias+relu, bf16 out --
__global__ __launch_bounds__(256) void k_agg1(const int* __restrict__ rowptr,
                                              const int* __restrict__ colv,
                                              const float* __restrict__ dinv,
                                              const unsigned int* __restrict__ Hs16,
                                              const float* __restrict__ b1,
                                              unsigned int* __restrict__ h1s16) {
    int wid = __builtin_amdgcn_readfirstlane((blockIdx.x * 256 + threadIdx.x) >> 6);
    if (wid >= N_NODES) return;
    int lane = threadIdx.x & 63;
    int f4 = lane & 3, sub = lane >> 2;
    int beg = rowptr[wid], end = rowptr[wid + 1];   // s_load (wid scalar)
    float dr = dinv[wid];                            // s_load
    float4 acc = make_float4(0.f, 0.f, 0.f, 0.f);
    for (int j = beg + sub; j < end; j += 16) {
        int c = colv[j];
        float dc = dinv[c];                          // 4 lanes share c
        uint2 hv = *reinterpret_cast<const uint2*>(Hs16 + (size_t)c * 8 + f4 * 2);
        acc.x = fmaf(bflo(hv.x), dc, acc.x);
        acc.y = fmaf(bfhi(hv.x), dc, acc.y);
        acc.z = fmaf(bflo(hv.y), dc, acc.z);
        acc.w = fmaf(bfhi(hv.y), dc, acc.w);
    }
#pragma unroll
    for (int d = 4; d < 64; d <<= 1) {
        acc.x += __shfl_xor(acc.x, d);
        acc.y += __shfl_xor(acc.y, d);
        acc.z += __shfl_xor(acc.z, d);
        acc.w += __shfl_xor(acc.w, d);
    }
    if (sub == 0) {
        uint2 sv = *reinterpret_cast<const uint2*>(Hs16 + (size_t)wid * 8 + f4 * 2);
        float4 bb = *reinterpret_cast<const float4*>(b1 + f4 * 4);
        float o0 = fmaxf((acc.x + bflo(sv.x) * dr) * dr + bb.x, 0.f) * dr;
        float o1 = fmaxf((acc.y + bfhi(sv.x) * dr) * dr + bb.y, 0.f) * dr;
        float o2 = fmaxf((acc.z + bflo(sv.y) * dr) * dr + bb.z, 0.f) * dr;
        float o3 = fmaxf((acc.w + bfhi(sv.y) * dr) * dr + bb.w, 0.f) * dr;
        uint2 pk;
        pk.x = f2bf(o0) | (f2bf(o1) << 16);
        pk.y = f2bf(o2) | (f2bf(o3) << 16);
        *reinterpret_cast<uint2*>(h1s16 + (size_t)wid * 8 + f4 * 2) = pk;
    }
}

// -- agg2: wave/node pull of bf16 h1s, fused 16x40 GEMM + bias -> out (f32) --
__global__ __launch_bounds__(256) void k_agg2(const int* __restrict__ rowptr,
                                              const int* __restrict__ colv,
                                              const float* __restrict__ dinv,
                                              const unsigned int* __restrict__ h1s16,
                                              const float* __restrict__ W2,
                                              const float* __restrict__ b2,
                                              float* __restrict__ out) {
    int wid = __builtin_amdgcn_readfirstlane((blockIdx.x * 256 + threadIdx.x) >> 6);
    if (wid >= N_NODES) return;
    int lane = threadIdx.x & 63;
    int f4 = lane & 3, sub = lane >> 2;
    int beg = rowptr[wid], end = rowptr[wid + 1];   // s_load
    float dr = dinv[wid];                            // s_load
    float4 acc = make_float4(0.f, 0.f, 0.f, 0.f);
    for (int j = beg + sub; j < end; j += 16) {
        int c = colv[j];
        uint2 hv = *reinterpret_cast<const uint2*>(h1s16 + (size_t)c * 8 + f4 * 2);
        acc.x += bflo(hv.x);
        acc.y += bfhi(hv.x);
        acc.z += bflo(hv.y);
        acc.w += bfhi(hv.y);
    }
#pragma unroll
    for (int d = 4; d < 64; d <<= 1) {
        acc.x += __shfl_xor(acc.x, d);
        acc.y += __shfl_xor(acc.y, d);
        acc.z += __shfl_xor(acc.z, d);
        acc.w += __shfl_xor(acc.w, d);
    }
    uint2 sv = *reinterpret_cast<const uint2*>(h1s16 + (size_t)wid * 8 + f4 * 2);
    float4 w4;
    w4.x = (acc.x + bflo(sv.x)) * dr;
    w4.y = (acc.y + bfhi(sv.x)) * dr;
    w4.z = (acc.z + bflo(sv.y)) * dr;
    w4.w = (acc.w + bfhi(sv.y)) * dr;
    if (lane < F_OUT) {
        float o = b2[lane];
#pragma unroll
        for (int k = 0; k < HID; ++k) {
            float comp = (k & 3) == 0 ? w4.x : (k & 3) == 1 ? w4.y
                        : (k & 3) == 2 ? w4.z : w4.w;
            float wk = __shfl(comp, k >> 2);   // lane k>>2 holds f4 == k>>2
            o = fmaf(wk, W2[k * F_OUT + lane], o);
        }
        out[(size_t)wid * F_OUT + lane] = o;
    }
}

// ---------------- launch ----------------
extern "C" void kernel_launch(void* const* d_in, const int* in_sizes, int n_in,
                              void* d_out, int out_size, void* d_ws, size_t ws_size,
                              hipStream_t stream) {
    const float* x  = (const float*)d_in[0];
    const int* ei   = (const int*)d_in[1];      // int32 [2][E]
    const float* W1 = (const float*)d_in[2];
    const float* b1 = (const float*)d_in[3];
    const float* W2 = (const float*)d_in[4];
    const float* b2 = (const float*)d_in[5];
    float* out = (float*)d_out;
    const int E = in_sizes[1] / 2;

    // ws layout (4B units)
    int* gcursor          = (int*)d_ws;                      // 12544
    int* rowptr           = gcursor + 12544;                 // 100016
    float* dinv           = (float*)(rowptr + 100016);       // 100032
    int* colv             = (int*)(dinv + 100032);           // 3,200,000
    unsigned int* sortbuf = (unsigned int*)(colv + 3200000); // 3,612,672
    unsigned int* h1s16   = sortbuf;                         // alias: dead after k_bg
    unsigned int* Hs16    = sortbuf + 3612672;               // 800,032 (bf16 x2)
    // total ~29 MB

    const int nbW = (N_NODES * 64 + 255) / 256;    // 25000 (wave per node)

    hipMemsetAsync(gcursor, 0, (size_t)NB * CUR_PAD * sizeof(int), stream);
    k_p1g<<<PARTB + G1, 512, 0, stream>>>(x, W1, ei, E, gcursor, sortbuf, Hs16);
    k_bg<<<NB + (NBG - G1), 512, 0, stream>>>(x, W1, sortbuf, gcursor,
                                              rowptr, dinv, colv, Hs16);
    k_agg1<<<nbW, 256, 0, stream>>>(rowptr, colv, dinv, Hs16, b1, h1s16);
    k_agg2<<<nbW, 256, 0, stream>>>(rowptr, colv, dinv, h1s16, W2, b2, out);
}